// Round 18
// baseline (465.681 us; speedup 1.0000x reference)
//
#include <hip/hip_runtime.h>
#include <hip/hip_bf16.h>
#include <stdint.h>

// Encoder pipeline, activations token-major [T=32768, C] bf16.
// prep(im2col K=192 | weights->bf16 | invperm | padw0) -> convGEMM(K=192,
// +b0,prelu) -> 3x { GEMM(+b, fused col-stats) -> bnfold -> bnact(prelu
// [, +pos,prelu am]) } -> mixGEMM(+bm, fp32, perm-scatter)
//
// GEMM: 256x256 block, BK=64, SIXTEEN waves (4M x 4N of 64x64 wave tiles),
// 1024 threads -> 4 waves/SIMD (TLP hides LDS latency; the 2-wave/SIMD
// variants plateaued at 38% MfmaUtil across 11 schedules).
// Single frag set (af/bf reused over kk) keeps VGPR <= 128 for 16-wave
// residency. r13 single-barrier drift skeleton: A dbuf, B TRIPLE-buffered:
//   gate(t): vmcnt(2) (drains A(t),B(t); leaves B(t+1) in flight); barrier;
//   ph1 {rd A/B kk0; stage A(t+1)->Abuf^1, B(t+2)->Bt[bS]; 16 MFMA}
//   ph2 {rd A/B kk1; 16 MFMA}; rotate.
// Staging: 1024 lanes x 16B = one 128-row half per gload instruction.
// LDS = 64KB (A) + 96KB (B) = 160KB.
// ws: B0(64MB) | B1(64MB) | part(2MB rsvd) | scsh(8KB) | inv(128KB) | weights(~7.5MB)

typedef __attribute__((ext_vector_type(8))) short bf16x8;
typedef __attribute__((ext_vector_type(4))) float f32x4;

__device__ __forceinline__ float bf2f(uint32_t u) {
  union { uint32_t i; float f; } v; v.i = u << 16; return v.f;
}
__device__ __forceinline__ ushort f2bf(float f) {
  union { float f; uint32_t i; } v; v.f = f;
  uint32_t i = v.i;
  return (ushort)((i + 0x7FFFu + ((i >> 16) & 1u)) >> 16);
}

// ---------------------------------------------------------------- GEMM
// Out[t,d] = sum_k A[t,k] * Bw[d,k]  (bf16, K-contiguous), fp32 accum.
// LDS K-major tiles, XOR chunk swizzle (slot = chunk ^ (row&7)); staged via
// global_load_lds with inverse-swizzled global source (both-sides rule).
// 1-D grid, XCD-grouping swizzle: 2^XB d-blocks sharing an A-slab run on one XCD.
// EPI: 0 = bias+prelu -> bf16
//      1 = bias -> bf16, + per-256-row-slab column sum/sumsq partials into `part`
//      2 = bias -> fp32, rows scattered via inverse permutation (mixer)
template<int EPI, int XB, int K, int DOUT>
__global__ void __launch_bounds__(1024, 4)
gemm_kernel(const ushort* __restrict__ A, const ushort* __restrict__ Bw,
            const float* __restrict__ bias, const float* __restrict__ alpha,
            void* __restrict__ outp, float* __restrict__ part,
            const int* __restrict__ inv)
{
  __shared__ __align__(16) ushort At[2][256 * 64];   // 64KB
  __shared__ __align__(16) ushort Bt[3][256 * 64];   // 96KB
  const int tid  = threadIdx.x;
  const int lane = tid & 63;
  const int wid  = tid >> 6;      // 0..15
  const int wm   = wid >> 2;      // 0..3  (M quarter: 64 rows)
  const int wn   = wid & 3;       // 0..3  (N quarter: 64 cols)

  // XCD-grouping swizzle: s = ((y>>3)*NX + x)*8 + (y&7)
  const int s = blockIdx.x;
  const int j = s >> 3;
  const int x = j & ((1 << XB) - 1);
  const int y = ((j >> XB) << 3) | (s & 7);
  const int t0 = y << 8;
  const int d0 = x << 8;

  f32x4 acc[4][4] = {};

  // ---- hoisted LDS read bases (byte offsets; swizzle term lane-constant) ----
  const int swz = (((lane >> 4) ^ (lane & 7)) << 4);     // kk=0 swizzle bytes
  const char* LA0 = (const char*)&At[0][0] + ((((wm << 6) + (lane & 15))) << 7) + swz;
  const char* LA1 = (const char*)&At[0][0] + ((((wm << 6) + (lane & 15))) << 7) + (swz ^ 64);
  const char* LB0 = (const char*)&Bt[0][0] + ((((wn << 6) + (lane & 15))) << 7) + swz;
  const char* LB1 = (const char*)&Bt[0][0] + ((((wn << 6) + (lane & 15))) << 7) + (swz ^ 64);

  // ---- hoisted staging bases (1024 threads: one 128-row half per instr) ----
  const int lrow8 = lane >> 3;             // row within wave's 8-row group
  const int csrc  = (lane & 7) ^ lrow8;    // inverse-swizzled source chunk
  const ushort* gAw = A  + (size_t)(t0 + (wid << 3) + lrow8) * K + (csrc << 3);
  const ushort* gBw = Bw + (size_t)(d0 + (wid << 3) + lrow8) * K + (csrc << 3);
  char* stA = (char*)&At[0][0] + (wid << 10);   // wave-uniform LDS dest base
  char* stB = (char*)&Bt[0][0] + (wid << 10);

#define STAGE_A(T, BUF, H) do {                                                          \
    __builtin_amdgcn_global_load_lds(                                                    \
      (const __attribute__((address_space(1))) uint32_t*)(gAw + (size_t)((H)*128)*K + ((size_t)(T) << 6)),     \
      (__attribute__((address_space(3))) uint32_t*)(stA + (BUF)*32768 + (H)*16384), 16, 0, 0);                  \
  } while (0)
#define STAGE_B(T, BOFF, H) do {                                                         \
    __builtin_amdgcn_global_load_lds(                                                    \
      (const __attribute__((address_space(1))) uint32_t*)(gBw + (size_t)((H)*128)*K + ((size_t)(T) << 6)),     \
      (__attribute__((address_space(3))) uint32_t*)(stB + (BOFF) + (H)*16384), 16, 0, 0);                       \
  } while (0)

#define RD4(dst, BASE, OFF) do {                                                         \
    dst[0] = *(const bf16x8*)((BASE) + (OFF) + 0);                                       \
    dst[1] = *(const bf16x8*)((BASE) + (OFF) + 2048);                                    \
    dst[2] = *(const bf16x8*)((BASE) + (OFF) + 4096);                                    \
    dst[3] = *(const bf16x8*)((BASE) + (OFF) + 6144);                                    \
  } while (0)
#define MFMA44(AF, BF) do {                                                              \
    __builtin_amdgcn_s_setprio(1);                                                       \
    _Pragma("unroll")                                                                    \
    for (int m_ = 0; m_ < 4; ++m_)                                                       \
      _Pragma("unroll")                                                                  \
      for (int n_ = 0; n_ < 4; ++n_)                                                     \
        acc[m_][n_] = __builtin_amdgcn_mfma_f32_16x16x32_bf16(                           \
            AF[m_], BF[n_], acc[m_][n_], 0, 0, 0);                                       \
    __builtin_amdgcn_s_setprio(0);                                                       \
  } while (0)

  // single barrier per K-tile; bR = B read offset, bS = stage target (t+2)
  // gate: vmcnt(2) drains A(t),B(t) (oldest 4 of 6), leaves B(t+1) in flight.
#define TILE_BODY(T, CUR, HN1, HN2) do {                                                 \
    if (HN1) { asm volatile("s_waitcnt vmcnt(2)" ::: "memory"); }                        \
    else     { asm volatile("s_waitcnt vmcnt(0)" ::: "memory"); }                        \
    __builtin_amdgcn_s_barrier();                                                        \
    RD4(af, LA0, (CUR)*32768);                                                           \
    RD4(bf_, LB0, bR);                                                                   \
    if (HN1) { STAGE_A((T) + 1, (CUR) ^ 1, 0); STAGE_A((T) + 1, (CUR) ^ 1, 1); }         \
    if (HN2) { STAGE_B((T) + 2, bS, 0); STAGE_B((T) + 2, bS, 1); }                       \
    MFMA44(af, bf_);                                                                     \
    RD4(af, LA1, (CUR)*32768);                                                           \
    RD4(bf_, LB1, bR);                                                                   \
    MFMA44(af, bf_);                                                                     \
    { int tmp_ = bR; bR = bN; bN = bS; bS = tmp_; }                                      \
  } while (0)

  constexpr int NT = K >> 6;   // 3 (conv) or 16 (layers/mixer)

  // prologue: tile0 A+B, tile1 B (A(1) staged during tile 0)
  STAGE_A(0, 0, 0); STAGE_A(0, 0, 1);
  STAGE_B(0, 0, 0); STAGE_B(0, 0, 1);
  STAGE_B(1, 32768, 0); STAGE_B(1, 32768, 1);

  int bR = 0, bN = 32768, bS = 65536;
  bf16x8 af[4], bf_[4];

  if constexpr ((NT & 1) == 0) {
#pragma unroll 1
    for (int tp = 0; tp < NT; tp += 2) {
      const bool m1 = (tp + 2 < NT);
      TILE_BODY(tp,     0, true, m1);
      TILE_BODY(tp + 1, 1, m1, m1);
    }
  } else {
#pragma unroll 1
    for (int t = 0; t < NT; ++t) {
      const int cur = t & 1;
      TILE_BODY(t, cur, (t + 1 < NT), (t + 2 < NT));
    }
  }

  // epilogue: C/D layout col = lane&15, row = (lane>>4)*4 + reg
  // m-outer / n-inner so the 4 chunks of each 128B line issue back-to-back.
  float bs[4];
#pragma unroll
  for (int n = 0; n < 4; ++n) bs[n] = bias[d0 + (wn << 6) + (n << 4) + (lane & 15)];
  float a0v = (EPI == 0) ? alpha[0] : 0.0f;
  float sA[4] = {0.f, 0.f, 0.f, 0.f}, s2A[4] = {0.f, 0.f, 0.f, 0.f};

#pragma unroll
  for (int m = 0; m < 4; ++m) {
#pragma unroll
    for (int r = 0; r < 4; ++r) {
      int row = t0 + (wm << 6) + (m << 4) + ((lane >> 4) << 2) + r;
      int orow = (EPI == 2) ? ((row & ~255) | inv[row]) : row;
#pragma unroll
      for (int n = 0; n < 4; ++n) {
        int d = d0 + (wn << 6) + (n << 4) + (lane & 15);
        float v = acc[m][n][r] + bs[n];
        if (EPI == 0) v = v > 0.f ? v : a0v * v;
        if (EPI == 1) { sA[n] += v; s2A[n] += v * v; }
        if (EPI == 2) ((float*)outp)[(size_t)orow * DOUT + d] = v;
        else          ((ushort*)outp)[(size_t)row * DOUT + d] = f2bf(v);
      }
    }
  }

  if (EPI == 1) {
    // deterministic per-block column reduction: 16 row-slots x 256 cols = 32KB
    float2* sm = (float2*)&At[0][0];            // At[0] = 32KB
    int slot = (wm << 2) | (lane >> 4);         // 0..15
    __syncthreads();
#pragma unroll
    for (int n = 0; n < 4; ++n) {
      int c = (wn << 6) + (n << 4) + (lane & 15);
      sm[slot * 256 + c] = make_float2(sA[n], s2A[n]);
    }
    __syncthreads();
    if (tid < 256) {
      float ss = 0.f, ss2 = 0.f;
      for (int q = 0; q < 16; ++q) {
        float2 v = sm[q * 256 + tid];
        ss += v.x; ss2 += v.y;
      }
      part[(size_t)y * 2048 + d0 + tid]        = ss;
      part[(size_t)y * 2048 + 1024 + d0 + tid] = ss2;
    }
  }
#undef STAGE_A
#undef STAGE_B
#undef RD4
#undef MFMA44
#undef TILE_BODY
}

// ------------------------------------------------------------ BN fold
__global__ void bnfold_kernel(const float* __restrict__ part, const float* __restrict__ g,
                              const float* __restrict__ bt, float* __restrict__ scsh) {
  int d = (blockIdx.x << 8) + threadIdx.x;    // grid 4
  float s = 0.f, s2 = 0.f;
  for (int j = 0; j < 128; ++j) { s += part[j * 2048 + d]; s2 += part[j * 2048 + 1024 + d]; }
  float mean = s * (1.f / 32768.f);
  float var  = s2 * (1.f / 32768.f) - mean * mean;
  float sc = g[d] * rsqrtf(var + 1e-5f);
  scsh[d] = sc;
  scsh[1024 + d] = bt[d] - mean * sc;
}

// y = prelu(y*sc + sh, p) [+ pos, prelu am], in place, 8 bf16/thread,
// grid-stride (2048 blocks x 8 iters).
template<bool MIX>
__global__ void bnact_kernel(ushort* __restrict__ Y, const float* __restrict__ scsh,
                             const float* __restrict__ p, const float* __restrict__ pos,
                             const float* __restrict__ am) {
  float pp = p[0];
  float aa = MIX ? am[0] : 0.f;
#pragma unroll 1
  for (int it = 0; it < 8; ++it) {
    size_t vi = ((size_t)it << 19) + ((size_t)blockIdx.x << 8) + threadIdx.x;  // vec idx
    size_t i = vi << 3;
    int d = (int)(i & 1023);
    float pv[8];
    if (MIX) {
      int prow = (int)((i >> 10) & 255);
      const float4* pb = (const float4*)(pos + ((size_t)prow << 10) + d);
      float4 pA = pb[0], pB = pb[1];
      pv[0]=pA.x; pv[1]=pA.y; pv[2]=pA.z; pv[3]=pA.w;
      pv[4]=pB.x; pv[5]=pB.y; pv[6]=pB.z; pv[7]=pB.w;
    }
    uint4 raw = *(const uint4*)(Y + i);
    uint32_t w[4] = {raw.x, raw.y, raw.z, raw.w};
    uint32_t o[4];
#pragma unroll
    for (int q = 0; q < 4; ++q) {
      int dd = d + q * 2;
      float v0 = bf2f(w[q] & 0xFFFFu) * scsh[dd]     + scsh[1024 + dd];
      float v1 = bf2f(w[q] >> 16)     * scsh[dd + 1] + scsh[1024 + dd + 1];
      v0 = v0 > 0.f ? v0 : pp * v0;
      v1 = v1 > 0.f ? v1 : pp * v1;
      if (MIX) {
        v0 += pv[2 * q];     v1 += pv[2 * q + 1];
        v0 = v0 > 0.f ? v0 : aa * v0;
        v1 = v1 > 0.f ? v1 : aa * v1;
      }
      o[q] = (uint32_t)f2bf(v0) | ((uint32_t)f2bf(v1) << 16);
    }
    *(uint4*)(Y + i) = make_uint4(o[0], o[1], o[2], o[3]);
  }
}

// ----------------------------------------------------------- fused preprocessing
// blocks [0,2048): im2col (16 tokens each, K padded 147->192)
// blocks [2048,4096): w1,w2,w3,wm -> bf16
// blocks [4096,4224): invperm
// blocks [4224,5248): padw0 (w0 -> bf16, K padded 147->192)
__global__ void prep_kernel(const float* __restrict__ x,
                            const float* __restrict__ w0, const float* __restrict__ w1,
                            const float* __restrict__ w2, const float* __restrict__ w3,
                            const float* __restrict__ wm, const int* __restrict__ perm,
                            ushort* __restrict__ P, ushort* __restrict__ w0b,
                            ushort* __restrict__ w1b, ushort* __restrict__ w2b,
                            ushort* __restrict__ w3b, ushort* __restrict__ wmb,
                            int* __restrict__ inv) {
  const int b = blockIdx.x, tid = threadIdx.x;
  if (b < 2048) {
    if (tid < 192) {
      int t0 = b << 4;
#pragma unroll 1
      for (int tt = 0; tt < 16; ++tt) {
        int t = t0 + tt;
        ushort v = 0;
        if (tid < 147) {
          int bb = t >> 8, pidx = t & 255;
          int pi = pidx >> 4, pj = pidx & 15;
          int cin = tid / 49, rem = tid - cin * 49;
          int dy = rem / 7, dx = rem - dy * 7;
          v = f2bf(x[(size_t)(bb * 3 + cin) * 12544 + (size_t)(pi * 7 + dy) * 112 + (pj * 7 + dx)]);
        }
        P[(size_t)t * 192 + tid] = v;
      }
    }
  } else if (b < 4096) {
    int i = ((b - 2048) << 8) + tid;           // [0, 524288)
#pragma unroll
    for (int r = 0; r < 2; ++r) {
      int idx = (r << 19) + i;
      w1b[idx] = f2bf(w1[idx]);
      w2b[idx] = f2bf(w2[idx]);
      w3b[idx] = f2bf(w3[idx]);
    }
    wmb[i] = f2bf(wm[i]);
  } else if (b < 4224) {
    int t = ((b - 4096) << 8) + tid;           // [0, 32768)
    inv[(t & ~255) + perm[t]] = t & 255;
  } else {
    int d = b - 4224;                          // [0, 1024)
    if (tid < 192)
      w0b[d * 192 + tid] = (tid < 147) ? f2bf(w0[d * 147 + tid]) : (ushort)0;
  }
}

extern "C" void kernel_launch(void* const* d_in, const int* in_sizes, int n_in,
                              void* d_out, int out_size, void* d_ws, size_t ws_size,
                              hipStream_t stream) {
  const float* x   = (const float*)d_in[0];
  const float* w0  = (const float*)d_in[1];
  const float* b0  = (const float*)d_in[2];
  const float* a0  = (const float*)d_in[3];
  const float* w1  = (const float*)d_in[4];
  const float* b1  = (const float*)d_in[5];
  const float* g1  = (const float*)d_in[6];
  const float* bt1 = (const float*)d_in[7];
  const float* p1  = (const float*)d_in[8];
  const float* w2  = (const float*)d_in[9];
  const float* b2  = (const float*)d_in[10];
  const float* g2  = (const float*)d_in[11];
  const float* bt2 = (const float*)d_in[12];
  const float* p2  = (const float*)d_in[13];
  const float* w3  = (const float*)d_in[14];
  const float* b3  = (const float*)d_in[15];
  const float* g3  = (const float*)d_in[16];
  const float* bt3 = (const float*)d_in[17];
  const float* p3  = (const float*)d_in[18];
  const float* pos = (const float*)d_in[19];
  const float* am  = (const float*)d_in[20];
  const float* wm  = (const float*)d_in[21];
  const float* bm  = (const float*)d_in[22];
  const int*  perm = (const int*)d_in[23];

  char* ws = (char*)d_ws;
  ushort* B0   = (ushort*)ws;                                   // 64MB
  ushort* B1   = (ushort*)(ws + 67108864);                      // 64MB
  float*  part = (float*)(ws + 134217728);                      // 1MB (2MB rsvd)
  float*  scsh = (float*)(ws + 134217728 + 2097152);            // 8KB
  int*    inv  = (int*)  (ws + 134217728 + 2097152 + 8192);     // 128KB
  char*   wb   = ws + 134217728 + 2097152 + 8192 + 131072;
  ushort* w1b  = (ushort*)wb;                                   // 2MB
  ushort* w2b  = w1b + 1048576;                                 // 2MB
  ushort* w3b  = w2b + 1048576;                                 // 2MB
  ushort* wmb  = w3b + 1048576;                                 // 1MB
  ushort* w0b  = wmb + 524288;                                  // 384KB (1024x192)

  // ---- all preprocessing in one dispatch ----
  prep_kernel<<<dim3(5248), dim3(256), 0, stream>>>(
      x, w0, w1, w2, w3, wm, perm, B1, w0b, w1b, w2b, w3b, wmb, inv);

  // patch-embed conv as GEMM: P(B1) x w0^T -> act0(B0), bias+prelu  (K=192)
  gemm_kernel<0, 2, 192, 1024><<<dim3(512), dim3(1024), 0, stream>>>(
      B1, w0b, b0, a0, (void*)B0, nullptr, nullptr);

  // layer 1: B0 -> B1  (stats fused)
  gemm_kernel<1, 2, 1024, 1024><<<dim3(512), dim3(1024), 0, stream>>>(
      B0, w1b, b1, nullptr, (void*)B1, part, nullptr);
  bnfold_kernel<<<dim3(4), dim3(256), 0, stream>>>(part, g1, bt1, scsh);
  bnact_kernel<false><<<dim3(2048), dim3(256), 0, stream>>>(B1, scsh, p1, nullptr, nullptr);

  // layer 2: B1 -> B0
  gemm_kernel<1, 2, 1024, 1024><<<dim3(512), dim3(1024), 0, stream>>>(
      B1, w2b, b2, nullptr, (void*)B0, part, nullptr);
  bnfold_kernel<<<dim3(4), dim3(256), 0, stream>>>(part, g2, bt2, scsh);
  bnact_kernel<false><<<dim3(2048), dim3(256), 0, stream>>>(B0, scsh, p2, nullptr, nullptr);

  // layer 3: B0 -> B1, bnact fused with +pos & prelu(am)
  gemm_kernel<1, 2, 1024, 1024><<<dim3(512), dim3(1024), 0, stream>>>(
      B0, w3b, b3, nullptr, (void*)B1, part, nullptr);
  bnfold_kernel<<<dim3(4), dim3(256), 0, stream>>>(part, g3, bt3, scsh);
  bnact_kernel<true><<<dim3(2048), dim3(256), 0, stream>>>(B1, scsh, p3, pos, am);

  // mixer: out = (enc @ wm^T + bm) rows scattered via inv -> d_out (fp32)
  gemm_kernel<2, 1, 1024, 512><<<dim3(256), dim3(1024), 0, stream>>>(
      B1, wmb, bm, nullptr, d_out, nullptr, inv);
}

// Round 19
// 384.044 us; speedup vs baseline: 1.2126x; 1.2126x over previous
//
#include <hip/hip_runtime.h>
#include <hip/hip_bf16.h>
#include <stdint.h>

// Encoder pipeline, activations token-major [T=32768, C] bf16.
// prep(im2col K=192 | weights->bf16 | invperm | padw0) -> convGEMM(K=192,
// +b0,prelu) -> 3x { GEMM(+b, fused col-stats) -> bnfold -> bnact(prelu
// [, +pos,prelu am]) } -> mixGEMM(+bm, fp32, perm-scatter)
//
// GEMM: 256x256 block, BK=64, 8 waves (2M x 4N), mfma_f32_16x16x32_bf16.
// Single-barrier drift skeleton (best of 12 variants; r18's 16-wave and
// r14's 32x32 both regressed with clean counter signatures):
//   gate(t): vmcnt(4) (drains A(t),B(t); leaves B(t+1) in flight); barrier;
//   4 phases {reads, MFMA}; stage A(t+1)->Abuf^1, B(t+2)->Bt[bS].
// A double-buffered, B TRIPLE-buffered (stage targets never read same tile).
// Even NT: compile-time paired loop. Odd NT (conv K=192): generic loop.
// LDS = 64KB (A) + 96KB (B) = 160KB.
// ws: B0(64MB) | B1(64MB) | part(2MB rsvd) | scsh(8KB) | inv(128KB) | weights(~7.5MB)

typedef __attribute__((ext_vector_type(8))) short bf16x8;
typedef __attribute__((ext_vector_type(4))) float f32x4;

__device__ __forceinline__ float bf2f(uint32_t u) {
  union { uint32_t i; float f; } v; v.i = u << 16; return v.f;
}
__device__ __forceinline__ ushort f2bf(float f) {
  union { float f; uint32_t i; } v; v.f = f;
  uint32_t i = v.i;
  return (ushort)((i + 0x7FFFu + ((i >> 16) & 1u)) >> 16);
}

// ---------------------------------------------------------------- GEMM
// Out[t,d] = sum_k A[t,k] * Bw[d,k]  (bf16, K-contiguous), fp32 accum.
// LDS K-major tiles, XOR chunk swizzle (slot = chunk ^ (row&7)); staged via
// global_load_lds with inverse-swizzled global source (both-sides rule).
// 1-D grid, XCD-grouping swizzle: 2^XB d-blocks sharing an A-slab run on one XCD.
// EPI: 0 = bias+prelu -> bf16
//      1 = bias -> bf16, + per-256-row-slab column sum/sumsq partials into `part`
//      2 = bias -> fp32, rows scattered via inverse permutation (mixer)
template<int EPI, int XB, int K, int DOUT>
__global__ void __launch_bounds__(512, 2)
gemm_kernel(const ushort* __restrict__ A, const ushort* __restrict__ Bw,
            const float* __restrict__ bias, const float* __restrict__ alpha,
            void* __restrict__ outp, float* __restrict__ part,
            const int* __restrict__ inv)
{
  __shared__ __align__(16) ushort At[2][256 * 64];   // 64KB
  __shared__ __align__(16) ushort Bt[3][256 * 64];   // 96KB
  const int tid  = threadIdx.x;
  const int lane = tid & 63;
  const int wid  = tid >> 6;      // 0..7
  const int wm   = wid >> 2;      // 0..1  (M half: 128 rows)
  const int wn   = wid & 3;       // 0..3  (N quarter: 64 cols)

  // XCD-grouping swizzle: s = ((y>>3)*NX + x)*8 + (y&7)
  const int s = blockIdx.x;
  const int j = s >> 3;
  const int x = j & ((1 << XB) - 1);
  const int y = ((j >> XB) << 3) | (s & 7);
  const int t0 = y << 8;
  const int d0 = x << 8;

  f32x4 acc[8][4] = {};

  // ---- hoisted LDS read bases (byte offsets; swizzle term lane-constant) ----
  const int swz = (((lane >> 4) ^ (lane & 7)) << 4);     // kk=0 swizzle bytes
  const char* LA0 = (const char*)&At[0][0] + ((((wm << 7) + (lane & 15))) << 7) + swz;
  const char* LA1 = (const char*)&At[0][0] + ((((wm << 7) + (lane & 15))) << 7) + (swz ^ 64);
  const char* LB0 = (const char*)&Bt[0][0] + ((((wn << 6) + (lane & 15))) << 7) + swz;
  const char* LB1 = (const char*)&Bt[0][0] + ((((wn << 6) + (lane & 15))) << 7) + (swz ^ 64);

  // ---- hoisted staging bases ----
  const int lrow8 = lane >> 3;             // row within 8-row staging group
  const int csrc  = (lane & 7) ^ lrow8;    // inverse-swizzled source chunk
  const ushort* gAw = A  + (size_t)(t0 + (wid << 4) + lrow8) * K + (csrc << 3);
  const ushort* gBw = Bw + (size_t)(d0 + (wid << 4) + lrow8) * K + (csrc << 3);
  char* stA = (char*)&At[0][0] + (wid << 11);   // wave-uniform LDS dest base
  char* stB = (char*)&Bt[0][0] + (wid << 11);

#define STAGE_A(T, BUF, H) do {                                                          \
    __builtin_amdgcn_global_load_lds(                                                    \
      (const __attribute__((address_space(1))) uint32_t*)(gAw + (size_t)((H)*128)*K + ((size_t)(T) << 6)),     \
      (__attribute__((address_space(3))) uint32_t*)(stA + (BUF)*32768 + (H)*16384), 16, 0, 0);                  \
    __builtin_amdgcn_global_load_lds(                                                    \
      (const __attribute__((address_space(1))) uint32_t*)(gAw + (size_t)((H)*128+8)*K + ((size_t)(T) << 6)),   \
      (__attribute__((address_space(3))) uint32_t*)(stA + (BUF)*32768 + (H)*16384 + 1024), 16, 0, 0);           \
  } while (0)
#define STAGE_B(T, BOFF, H) do {                                                         \
    __builtin_amdgcn_global_load_lds(                                                    \
      (const __attribute__((address_space(1))) uint32_t*)(gBw + (size_t)((H)*128)*K + ((size_t)(T) << 6)),     \
      (__attribute__((address_space(3))) uint32_t*)(stB + (BOFF) + (H)*16384), 16, 0, 0);                       \
    __builtin_amdgcn_global_load_lds(                                                    \
      (const __attribute__((address_space(1))) uint32_t*)(gBw + (size_t)((H)*128+8)*K + ((size_t)(T) << 6)),   \
      (__attribute__((address_space(3))) uint32_t*)(stB + (BOFF) + (H)*16384 + 1024), 16, 0, 0);                \
  } while (0)

#define RD_A(dst, BASE, CUR, MH) do {                                                    \
    dst[0] = *(const bf16x8*)((BASE) + (CUR)*32768 + (MH)*8192 + 0);                     \
    dst[1] = *(const bf16x8*)((BASE) + (CUR)*32768 + (MH)*8192 + 2048);                  \
    dst[2] = *(const bf16x8*)((BASE) + (CUR)*32768 + (MH)*8192 + 4096);                  \
    dst[3] = *(const bf16x8*)((BASE) + (CUR)*32768 + (MH)*8192 + 6144);                  \
  } while (0)
#define RD_B(dst, BASE, BOFF) do {                                                       \
    dst[0] = *(const bf16x8*)((BASE) + (BOFF) + 0);                                      \
    dst[1] = *(const bf16x8*)((BASE) + (BOFF) + 2048);                                   \
    dst[2] = *(const bf16x8*)((BASE) + (BOFF) + 4096);                                   \
    dst[3] = *(const bf16x8*)((BASE) + (BOFF) + 6144);                                   \
  } while (0)
#define MFMA16(AF, BF, MH) do {                                                          \
    __builtin_amdgcn_s_setprio(1);                                                       \
    _Pragma("unroll")                                                                    \
    for (int m_ = 0; m_ < 4; ++m_)                                                       \
      _Pragma("unroll")                                                                  \
      for (int n_ = 0; n_ < 4; ++n_)                                                     \
        acc[((MH) << 2) + m_][n_] = __builtin_amdgcn_mfma_f32_16x16x32_bf16(             \
            AF[m_], BF[n_], acc[((MH) << 2) + m_][n_], 0, 0, 0);                         \
    __builtin_amdgcn_s_setprio(0);                                                       \
  } while (0)

  // single barrier per K-tile; bR = B buf read offset, bS = stage target (t+2)
  // gate: vmcnt(4) drains A(t),B(t) (oldest 8 of 12), leaves B(t+1) in flight.
#define TILE_BODY(T, CUR, HN1, HN2) do {                                                 \
    if (HN1) { asm volatile("s_waitcnt vmcnt(4)" ::: "memory"); }                        \
    else     { asm volatile("s_waitcnt vmcnt(0)" ::: "memory"); }                        \
    __builtin_amdgcn_s_barrier();                                                        \
    RD_A(aX, LA0, CUR, 0);                                                               \
    RD_B(b0f, LB0, bR);                                                                  \
    if (HN1) { STAGE_A((T) + 1, (CUR) ^ 1, 0); STAGE_A((T) + 1, (CUR) ^ 1, 1); }         \
    if (HN2) { STAGE_B((T) + 2, bS, 0); STAGE_B((T) + 2, bS, 1); }                       \
    MFMA16(aX, b0f, 0);                                                                  \
    RD_A(aY, LA0, CUR, 1);                                                               \
    MFMA16(aY, b0f, 1);                                                                  \
    RD_A(aX, LA1, CUR, 0);                                                               \
    RD_B(b1f, LB1, bR);                                                                  \
    MFMA16(aX, b1f, 0);                                                                  \
    RD_A(aY, LA1, CUR, 1);                                                               \
    MFMA16(aY, b1f, 1);                                                                  \
    { int tmp_ = bR; bR = bN; bN = bS; bS = tmp_; }                                      \
  } while (0)

  constexpr int NT = K >> 6;   // 3 (conv, K=192) or 16 (layers/mixer)

  // prologue: tile0 A+B, tile1 B (A(1) staged during tile 0)
  STAGE_A(0, 0, 0); STAGE_A(0, 0, 1);
  STAGE_B(0, 0, 0); STAGE_B(0, 0, 1);
  STAGE_B(1, 32768, 0); STAGE_B(1, 32768, 1);

  int bR = 0, bN = 32768, bS = 65536;
  bf16x8 aX[4], aY[4], b0f[4], b1f[4];

  if constexpr ((NT & 1) == 0) {
#pragma unroll 1
    for (int tp = 0; tp < NT; tp += 2) {
      const bool m1 = (tp + 2 < NT);
      TILE_BODY(tp,     0, true, m1);
      TILE_BODY(tp + 1, 1, m1, m1);
    }
  } else {
#pragma unroll 1
    for (int t = 0; t < NT; ++t) {
      const int cur = t & 1;
      TILE_BODY(t, cur, (t + 1 < NT), (t + 2 < NT));
    }
  }

  // epilogue: C/D layout col = lane&15, row = (lane>>4)*4 + reg
  // m-outer / n-inner so the 4 chunks of each 128B line issue back-to-back.
  float bs[4];
#pragma unroll
  for (int n = 0; n < 4; ++n) bs[n] = bias[d0 + (wn << 6) + (n << 4) + (lane & 15)];
  float a0v = (EPI == 0) ? alpha[0] : 0.0f;
  float sA[4] = {0.f, 0.f, 0.f, 0.f}, s2A[4] = {0.f, 0.f, 0.f, 0.f};

#pragma unroll
  for (int m = 0; m < 8; ++m) {
#pragma unroll
    for (int r = 0; r < 4; ++r) {
      int row = t0 + (wm << 7) + (m << 4) + ((lane >> 4) << 2) + r;
      int orow = (EPI == 2) ? ((row & ~255) | inv[row]) : row;
#pragma unroll
      for (int n = 0; n < 4; ++n) {
        int d = d0 + (wn << 6) + (n << 4) + (lane & 15);
        float v = acc[m][n][r] + bs[n];
        if (EPI == 0) v = v > 0.f ? v : a0v * v;
        if (EPI == 1) { sA[n] += v; s2A[n] += v * v; }
        if (EPI == 2) ((float*)outp)[(size_t)orow * DOUT + d] = v;
        else          ((ushort*)outp)[(size_t)row * DOUT + d] = f2bf(v);
      }
    }
  }

  if (EPI == 1) {
    // deterministic per-block column reduction (256 cols), one slab row of partials.
    float2* sm = (float2*)&At[0][0];            // 8 x 256 float2 = 16KB
    int slot = (wm << 2) | (lane >> 4);         // 0..7
    __syncthreads();
#pragma unroll
    for (int n = 0; n < 4; ++n) {
      int c = (wn << 6) + (n << 4) + (lane & 15);
      sm[slot * 256 + c] = make_float2(sA[n], s2A[n]);
    }
    __syncthreads();
    if (tid < 256) {
      float ss = 0.f, ss2 = 0.f;
      for (int q = 0; q < 8; ++q) {
        float2 v = sm[q * 256 + tid];
        ss += v.x; ss2 += v.y;
      }
      part[(size_t)y * 2048 + d0 + tid]        = ss;
      part[(size_t)y * 2048 + 1024 + d0 + tid] = ss2;
    }
  }
#undef STAGE_A
#undef STAGE_B
#undef RD_A
#undef RD_B
#undef MFMA16
#undef TILE_BODY
}

// ------------------------------------------------------------ BN fold
__global__ void bnfold_kernel(const float* __restrict__ part, const float* __restrict__ g,
                              const float* __restrict__ bt, float* __restrict__ scsh) {
  int d = (blockIdx.x << 8) + threadIdx.x;    // grid 4
  float s = 0.f, s2 = 0.f;
  for (int j = 0; j < 128; ++j) { s += part[j * 2048 + d]; s2 += part[j * 2048 + 1024 + d]; }
  float mean = s * (1.f / 32768.f);
  float var  = s2 * (1.f / 32768.f) - mean * mean;
  float sc = g[d] * rsqrtf(var + 1e-5f);
  scsh[d] = sc;
  scsh[1024 + d] = bt[d] - mean * sc;
}

// y = prelu(y*sc + sh, p) [+ pos, prelu am], in place, 8 bf16/thread,
// grid-stride (2048 blocks x 8 iters).
template<bool MIX>
__global__ void bnact_kernel(ushort* __restrict__ Y, const float* __restrict__ scsh,
                             const float* __restrict__ p, const float* __restrict__ pos,
                             const float* __restrict__ am) {
  float pp = p[0];
  float aa = MIX ? am[0] : 0.f;
#pragma unroll 1
  for (int it = 0; it < 8; ++it) {
    size_t vi = ((size_t)it << 19) + ((size_t)blockIdx.x << 8) + threadIdx.x;  // vec idx
    size_t i = vi << 3;
    int d = (int)(i & 1023);
    float pv[8];
    if (MIX) {
      int prow = (int)((i >> 10) & 255);
      const float4* pb = (const float4*)(pos + ((size_t)prow << 10) + d);
      float4 pA = pb[0], pB = pb[1];
      pv[0]=pA.x; pv[1]=pA.y; pv[2]=pA.z; pv[3]=pA.w;
      pv[4]=pB.x; pv[5]=pB.y; pv[6]=pB.z; pv[7]=pB.w;
    }
    uint4 raw = *(const uint4*)(Y + i);
    uint32_t w[4] = {raw.x, raw.y, raw.z, raw.w};
    uint32_t o[4];
#pragma unroll
    for (int q = 0; q < 4; ++q) {
      int dd = d + q * 2;
      float v0 = bf2f(w[q] & 0xFFFFu) * scsh[dd]     + scsh[1024 + dd];
      float v1 = bf2f(w[q] >> 16)     * scsh[dd + 1] + scsh[1024 + dd + 1];
      v0 = v0 > 0.f ? v0 : pp * v0;
      v1 = v1 > 0.f ? v1 : pp * v1;
      if (MIX) {
        v0 += pv[2 * q];     v1 += pv[2 * q + 1];
        v0 = v0 > 0.f ? v0 : aa * v0;
        v1 = v1 > 0.f ? v1 : aa * v1;
      }
      o[q] = (uint32_t)f2bf(v0) | ((uint32_t)f2bf(v1) << 16);
    }
    *(uint4*)(Y + i) = make_uint4(o[0], o[1], o[2], o[3]);
  }
}

// ----------------------------------------------------------- fused preprocessing
// blocks [0,2048): im2col (16 tokens each, K padded 147->192)
// blocks [2048,4096): w1,w2,w3,wm -> bf16
// blocks [4096,4224): invperm
// blocks [4224,5248): padw0 (w0 -> bf16, K padded 147->192)
__global__ void prep_kernel(const float* __restrict__ x,
                            const float* __restrict__ w0, const float* __restrict__ w1,
                            const float* __restrict__ w2, const float* __restrict__ w3,
                            const float* __restrict__ wm, const int* __restrict__ perm,
                            ushort* __restrict__ P, ushort* __restrict__ w0b,
                            ushort* __restrict__ w1b, ushort* __restrict__ w2b,
                            ushort* __restrict__ w3b, ushort* __restrict__ wmb,
                            int* __restrict__ inv) {
  const int b = blockIdx.x, tid = threadIdx.x;
  if (b < 2048) {
    if (tid < 192) {
      int t0 = b << 4;
#pragma unroll 1
      for (int tt = 0; tt < 16; ++tt) {
        int t = t0 + tt;
        ushort v = 0;
        if (tid < 147) {
          int bb = t >> 8, pidx = t & 255;
          int pi = pidx >> 4, pj = pidx & 15;
          int cin = tid / 49, rem = tid - cin * 49;
          int dy = rem / 7, dx = rem - dy * 7;
          v = f2bf(x[(size_t)(bb * 3 + cin) * 12544 + (size_t)(pi * 7 + dy) * 112 + (pj * 7 + dx)]);
        }
        P[(size_t)t * 192 + tid] = v;
      }
    }
  } else if (b < 4096) {
    int i = ((b - 2048) << 8) + tid;           // [0, 524288)
#pragma unroll
    for (int r = 0; r < 2; ++r) {
      int idx = (r << 19) + i;
      w1b[idx] = f2bf(w1[idx]);
      w2b[idx] = f2bf(w2[idx]);
      w3b[idx] = f2bf(w3[idx]);
    }
    wmb[i] = f2bf(wm[i]);
  } else if (b < 4224) {
    int t = ((b - 4096) << 8) + tid;           // [0, 32768)
    inv[(t & ~255) + perm[t]] = t & 255;
  } else {
    int d = b - 4224;                          // [0, 1024)
    if (tid < 192)
      w0b[d * 192 + tid] = (tid < 147) ? f2bf(w0[d * 147 + tid]) : (ushort)0;
  }
}

extern "C" void kernel_launch(void* const* d_in, const int* in_sizes, int n_in,
                              void* d_out, int out_size, void* d_ws, size_t ws_size,
                              hipStream_t stream) {
  const float* x   = (const float*)d_in[0];
  const float* w0  = (const float*)d_in[1];
  const float* b0  = (const float*)d_in[2];
  const float* a0  = (const float*)d_in[3];
  const float* w1  = (const float*)d_in[4];
  const float* b1  = (const float*)d_in[5];
  const float* g1  = (const float*)d_in[6];
  const float* bt1 = (const float*)d_in[7];
  const float* p1  = (const float*)d_in[8];
  const float* w2  = (const float*)d_in[9];
  const float* b2  = (const float*)d_in[10];
  const float* g2  = (const float*)d_in[11];
  const float* bt2 = (const float*)d_in[12];
  const float* p2  = (const float*)d_in[13];
  const float* w3  = (const float*)d_in[14];
  const float* b3  = (const float*)d_in[15];
  const float* g3  = (const float*)d_in[16];
  const float* bt3 = (const float*)d_in[17];
  const float* p3  = (const float*)d_in[18];
  const float* pos = (const float*)d_in[19];
  const float* am  = (const float*)d_in[20];
  const float* wm  = (const float*)d_in[21];
  const float* bm  = (const float*)d_in[22];
  const int*  perm = (const int*)d_in[23];

  char* ws = (char*)d_ws;
  ushort* B0   = (ushort*)ws;                                   // 64MB
  ushort* B1   = (ushort*)(ws + 67108864);                      // 64MB
  float*  part = (float*)(ws + 134217728);                      // 1MB (2MB rsvd)
  float*  scsh = (float*)(ws + 134217728 + 2097152);            // 8KB
  int*    inv  = (int*)  (ws + 134217728 + 2097152 + 8192);     // 128KB
  char*   wb   = ws + 134217728 + 2097152 + 8192 + 131072;
  ushort* w1b  = (ushort*)wb;                                   // 2MB
  ushort* w2b  = w1b + 1048576;                                 // 2MB
  ushort* w3b  = w2b + 1048576;                                 // 2MB
  ushort* wmb  = w3b + 1048576;                                 // 1MB
  ushort* w0b  = wmb + 524288;                                  // 384KB (1024x192)

  // ---- all preprocessing in one dispatch ----
  prep_kernel<<<dim3(5248), dim3(256), 0, stream>>>(
      x, w0, w1, w2, w3, wm, perm, B1, w0b, w1b, w2b, w3b, wmb, inv);

  // patch-embed conv as GEMM: P(B1) x w0^T -> act0(B0), bias+prelu  (K=192)
  gemm_kernel<0, 2, 192, 1024><<<dim3(512), dim3(512), 0, stream>>>(
      B1, w0b, b0, a0, (void*)B0, nullptr, nullptr);

  // layer 1: B0 -> B1  (stats fused)
  gemm_kernel<1, 2, 1024, 1024><<<dim3(512), dim3(512), 0, stream>>>(
      B0, w1b, b1, nullptr, (void*)B1, part, nullptr);
  bnfold_kernel<<<dim3(4), dim3(256), 0, stream>>>(part, g1, bt1, scsh);
  bnact_kernel<false><<<dim3(2048), dim3(256), 0, stream>>>(B1, scsh, p1, nullptr, nullptr);

  // layer 2: B1 -> B0
  gemm_kernel<1, 2, 1024, 1024><<<dim3(512), dim3(512), 0, stream>>>(
      B1, w2b, b2, nullptr, (void*)B0, part, nullptr);
  bnfold_kernel<<<dim3(4), dim3(256), 0, stream>>>(part, g2, bt2, scsh);
  bnact_kernel<false><<<dim3(2048), dim3(256), 0, stream>>>(B0, scsh, p2, nullptr, nullptr);

  // layer 3: B0 -> B1, bnact fused with +pos & prelu(am)
  gemm_kernel<1, 2, 1024, 1024><<<dim3(512), dim3(512), 0, stream>>>(
      B0, w3b, b3, nullptr, (void*)B1, part, nullptr);
  bnfold_kernel<<<dim3(4), dim3(256), 0, stream>>>(part, g3, bt3, scsh);
  bnact_kernel<true><<<dim3(2048), dim3(256), 0, stream>>>(B1, scsh, p3, pos, am);

  // mixer: out = (enc @ wm^T + bm) rows scattered via inv -> d_out (fp32)
  gemm_kernel<2, 1, 1024, 512><<<dim3(256), dim3(512), 0, stream>>>(
      B1, wmb, bm, nullptr, d_out, nullptr, inv);
}

// Round 20
// 382.513 us; speedup vs baseline: 1.2174x; 1.0040x over previous
//
#include <hip/hip_runtime.h>
#include <hip/hip_bf16.h>
#include <stdint.h>

// Encoder pipeline, activations token-major [T=32768, C] bf16.
// prep(im2col K=192 | weights->bf16 | invperm | padw0) -> convGEMM(K=192,
// +b0,prelu) -> 3x { GEMM(+b, fused col-stats) -> bnfold -> bnact(prelu
// [, +pos,prelu am]) } -> mixGEMM(+bm, fp32, perm-scatter)
//
// GEMM: 256x256 block, BK=64, 8 waves (2M x 4N), mfma_f32_16x16x32_bf16.
// r8 two-barrier drift body (fastest of 13 variants; all 5 r8 samples beat
// all 5 single-barrier samples):
//   gate(t): vmcnt(4) [drains A(t),B(t); leaves B(t+1) in flight]; barrier
//   ph1: rdA(mh0,k0)+rdB(k0); stage A(t+1)->Abuf^1; MFMA
//   ph2: rdA(mh1,k0); MFMA    ph3: rdA(mh0,k1)+rdB(k1); MFMA
//   mid-barrier (all B reads of Bbuf[cur] returned); stage B(t+2)->Bbuf[cur]
//   ph4: rdA(mh1,k1); MFMA
// A,B double-buffered; LDS = 64KB + 64KB = 128KB.
// Even NT: compile-time paired loop. Odd NT (conv K=192, NT=3): generic loop
// (rotation traced safe: gate(0) leaves B1; mid(0) B2->buf0 post-barrier).
// ws: B0(64MB) | B1(64MB) | part(2MB rsvd) | scsh(8KB) | inv(128KB) | weights(~7.5MB)

typedef __attribute__((ext_vector_type(8))) short bf16x8;
typedef __attribute__((ext_vector_type(4))) float f32x4;

__device__ __forceinline__ float bf2f(uint32_t u) {
  union { uint32_t i; float f; } v; v.i = u << 16; return v.f;
}
__device__ __forceinline__ ushort f2bf(float f) {
  union { float f; uint32_t i; } v; v.f = f;
  uint32_t i = v.i;
  return (ushort)((i + 0x7FFFu + ((i >> 16) & 1u)) >> 16);
}

// ---------------------------------------------------------------- GEMM
// Out[t,d] = sum_k A[t,k] * Bw[d,k]  (bf16, K-contiguous), fp32 accum.
// LDS K-major tiles, XOR chunk swizzle (slot = chunk ^ (row&7)); staged via
// global_load_lds with inverse-swizzled global source (both-sides rule).
// 1-D grid, XCD-grouping swizzle: 2^XB d-blocks sharing an A-slab run on one XCD.
// EPI: 0 = bias+prelu -> bf16
//      1 = bias -> bf16, + per-256-row-slab column sum/sumsq partials into `part`
//      2 = bias -> fp32, rows scattered via inverse permutation (mixer)
template<int EPI, int XB, int K, int DOUT>
__global__ void __launch_bounds__(512, 2)
gemm_kernel(const ushort* __restrict__ A, const ushort* __restrict__ Bw,
            const float* __restrict__ bias, const float* __restrict__ alpha,
            void* __restrict__ outp, float* __restrict__ part,
            const int* __restrict__ inv)
{
  __shared__ __align__(16) ushort At[2][256 * 64];   // 64KB
  __shared__ __align__(16) ushort Bt[2][256 * 64];   // 64KB
  const int tid  = threadIdx.x;
  const int lane = tid & 63;
  const int wid  = tid >> 6;      // 0..7
  const int wm   = wid >> 2;      // 0..1  (M half: 128 rows)
  const int wn   = wid & 3;       // 0..3  (N quarter: 64 cols)

  // XCD-grouping swizzle: s = ((y>>3)*NX + x)*8 + (y&7)
  const int s = blockIdx.x;
  const int j = s >> 3;
  const int x = j & ((1 << XB) - 1);
  const int y = ((j >> XB) << 3) | (s & 7);
  const int t0 = y << 8;
  const int d0 = x << 8;

  f32x4 acc[8][4] = {};

  // ---- hoisted LDS read bases (byte offsets; swizzle term lane-constant) ----
  const int swz = (((lane >> 4) ^ (lane & 7)) << 4);     // kk=0 swizzle bytes
  const char* LA0 = (const char*)&At[0][0] + ((((wm << 7) + (lane & 15))) << 7) + swz;
  const char* LA1 = (const char*)&At[0][0] + ((((wm << 7) + (lane & 15))) << 7) + (swz ^ 64);
  const char* LB0 = (const char*)&Bt[0][0] + ((((wn << 6) + (lane & 15))) << 7) + swz;
  const char* LB1 = (const char*)&Bt[0][0] + ((((wn << 6) + (lane & 15))) << 7) + (swz ^ 64);

  // ---- hoisted staging bases ----
  const int lrow8 = lane >> 3;             // row within 8-row staging group
  const int csrc  = (lane & 7) ^ lrow8;    // inverse-swizzled source chunk
  const ushort* gAw = A  + (size_t)(t0 + (wid << 4) + lrow8) * K + (csrc << 3);
  const ushort* gBw = Bw + (size_t)(d0 + (wid << 4) + lrow8) * K + (csrc << 3);
  char* stA = (char*)&At[0][0] + (wid << 11);   // wave-uniform LDS dest base
  char* stB = (char*)&Bt[0][0] + (wid << 11);

#define STAGE_A(T, BUF, H) do {                                                          \
    __builtin_amdgcn_global_load_lds(                                                    \
      (const __attribute__((address_space(1))) uint32_t*)(gAw + (size_t)((H)*128)*K + ((size_t)(T) << 6)),     \
      (__attribute__((address_space(3))) uint32_t*)(stA + (BUF)*32768 + (H)*16384), 16, 0, 0);                  \
    __builtin_amdgcn_global_load_lds(                                                    \
      (const __attribute__((address_space(1))) uint32_t*)(gAw + (size_t)((H)*128+8)*K + ((size_t)(T) << 6)),   \
      (__attribute__((address_space(3))) uint32_t*)(stA + (BUF)*32768 + (H)*16384 + 1024), 16, 0, 0);           \
  } while (0)
#define STAGE_B(T, BUF, H) do {                                                          \
    __builtin_amdgcn_global_load_lds(                                                    \
      (const __attribute__((address_space(1))) uint32_t*)(gBw + (size_t)((H)*128)*K + ((size_t)(T) << 6)),     \
      (__attribute__((address_space(3))) uint32_t*)(stB + (BUF)*32768 + (H)*16384), 16, 0, 0);                  \
    __builtin_amdgcn_global_load_lds(                                                    \
      (const __attribute__((address_space(1))) uint32_t*)(gBw + (size_t)((H)*128+8)*K + ((size_t)(T) << 6)),   \
      (__attribute__((address_space(3))) uint32_t*)(stB + (BUF)*32768 + (H)*16384 + 1024), 16, 0, 0);           \
  } while (0)

#define RD_A(dst, BASE, CUR, MH) do {                                                    \
    dst[0] = *(const bf16x8*)((BASE) + (CUR)*32768 + (MH)*8192 + 0);                     \
    dst[1] = *(const bf16x8*)((BASE) + (CUR)*32768 + (MH)*8192 + 2048);                  \
    dst[2] = *(const bf16x8*)((BASE) + (CUR)*32768 + (MH)*8192 + 4096);                  \
    dst[3] = *(const bf16x8*)((BASE) + (CUR)*32768 + (MH)*8192 + 6144);                  \
  } while (0)
#define RD_B(dst, BASE, CUR) do {                                                        \
    dst[0] = *(const bf16x8*)((BASE) + (CUR)*32768 + 0);                                 \
    dst[1] = *(const bf16x8*)((BASE) + (CUR)*32768 + 2048);                              \
    dst[2] = *(const bf16x8*)((BASE) + (CUR)*32768 + 4096);                              \
    dst[3] = *(const bf16x8*)((BASE) + (CUR)*32768 + 6144);                              \
  } while (0)
#define MFMA16(AF, BF, MH) do {                                                          \
    __builtin_amdgcn_s_setprio(1);                                                       \
    _Pragma("unroll")                                                                    \
    for (int m_ = 0; m_ < 4; ++m_)                                                       \
      _Pragma("unroll")                                                                  \
      for (int n_ = 0; n_ < 4; ++n_)                                                     \
        acc[((MH) << 2) + m_][n_] = __builtin_amdgcn_mfma_f32_16x16x32_bf16(             \
            AF[m_], BF[n_], acc[((MH) << 2) + m_][n_], 0, 0, 0);                         \
    __builtin_amdgcn_s_setprio(0);                                                       \
  } while (0)

#define TILE_BODY(T, CUR, HN1, HN2) do {                                                 \
    /* gate: tile T fully landed; B(T+1) may stay in flight */                           \
    if (HN1) { asm volatile("s_waitcnt vmcnt(4)" ::: "memory"); }                        \
    else     { asm volatile("s_waitcnt vmcnt(0)" ::: "memory"); }                        \
    __builtin_amdgcn_s_barrier();                                                        \
    /* ph1 */                                                                            \
    RD_A(aX, LA0, CUR, 0);                                                               \
    RD_B(b0f, LB0, CUR);                                                                 \
    if (HN1) { STAGE_A((T) + 1, (CUR) ^ 1, 0); STAGE_A((T) + 1, (CUR) ^ 1, 1); }         \
    MFMA16(aX, b0f, 0);                                                                  \
    /* ph2 */                                                                            \
    RD_A(aY, LA0, CUR, 1);                                                               \
    MFMA16(aY, b0f, 1);                                                                  \
    /* ph3 */                                                                            \
    RD_A(aX, LA1, CUR, 0);                                                               \
    RD_B(b1f, LB1, CUR);                                                                 \
    MFMA16(aX, b1f, 0);                                                                  \
    /* all waves' B reads of Bbuf[CUR] returned (b1f consumed above) */                  \
    __builtin_amdgcn_s_barrier();                                                        \
    if (HN2) { STAGE_B((T) + 2, CUR, 0); STAGE_B((T) + 2, CUR, 1); }                     \
    /* ph4 (A-region reads; disjoint from B(t+2) writes) */                              \
    RD_A(aY, LA1, CUR, 1);                                                               \
    MFMA16(aY, b1f, 1);                                                                  \
  } while (0)

  constexpr int NT = K >> 6;   // 3 (conv, K=192) or 16 (layers/mixer)

  // prologue: tile0 A+B, tile1 B (A(1) staged during tile 0 ph1)
  STAGE_A(0, 0, 0); STAGE_A(0, 0, 1);
  STAGE_B(0, 0, 0); STAGE_B(0, 0, 1);
  STAGE_B(1, 1, 0); STAGE_B(1, 1, 1);

  bf16x8 aX[4], aY[4], b0f[4], b1f[4];

  if constexpr ((NT & 1) == 0) {
#pragma unroll 1
    for (int tp = 0; tp < NT; tp += 2) {
      const bool m1 = (tp + 2 < NT);
      TILE_BODY(tp,     0, true, m1);
      TILE_BODY(tp + 1, 1, m1, m1);
    }
  } else {
#pragma unroll 1
    for (int t = 0; t < NT; ++t) {
      const int cur = t & 1;
      TILE_BODY(t, cur, (t + 1 < NT), (t + 2 < NT));
    }
  }

  // epilogue: C/D layout col = lane&15, row = (lane>>4)*4 + reg
  // m-outer / n-inner so the 4 chunks of each 128B line issue back-to-back.
  float bs[4];
#pragma unroll
  for (int n = 0; n < 4; ++n) bs[n] = bias[d0 + (wn << 6) + (n << 4) + (lane & 15)];
  float a0v = (EPI == 0) ? alpha[0] : 0.0f;
  float sA[4] = {0.f, 0.f, 0.f, 0.f}, s2A[4] = {0.f, 0.f, 0.f, 0.f};

#pragma unroll
  for (int m = 0; m < 8; ++m) {
#pragma unroll
    for (int r = 0; r < 4; ++r) {
      int row = t0 + (wm << 7) + (m << 4) + ((lane >> 4) << 2) + r;
      int orow = (EPI == 2) ? ((row & ~255) | inv[row]) : row;
#pragma unroll
      for (int n = 0; n < 4; ++n) {
        int d = d0 + (wn << 6) + (n << 4) + (lane & 15);
        float v = acc[m][n][r] + bs[n];
        if (EPI == 0) v = v > 0.f ? v : a0v * v;
        if (EPI == 1) { sA[n] += v; s2A[n] += v * v; }
        if (EPI == 2) ((float*)outp)[(size_t)orow * DOUT + d] = v;
        else          ((ushort*)outp)[(size_t)row * DOUT + d] = f2bf(v);
      }
    }
  }

  if (EPI == 1) {
    // deterministic per-block column reduction (256 cols), one slab row of partials.
    float2* sm = (float2*)&At[0][0];            // 8 x 256 float2 = 16KB
    int slot = (wm << 2) | (lane >> 4);         // 0..7
    __syncthreads();
#pragma unroll
    for (int n = 0; n < 4; ++n) {
      int c = (wn << 6) + (n << 4) + (lane & 15);
      sm[slot * 256 + c] = make_float2(sA[n], s2A[n]);
    }
    __syncthreads();
    if (tid < 256) {
      float ss = 0.f, ss2 = 0.f;
      for (int q = 0; q < 8; ++q) {
        float2 v = sm[q * 256 + tid];
        ss += v.x; ss2 += v.y;
      }
      part[(size_t)y * 2048 + d0 + tid]        = ss;
      part[(size_t)y * 2048 + 1024 + d0 + tid] = ss2;
    }
  }
#undef STAGE_A
#undef STAGE_B
#undef RD_A
#undef RD_B
#undef MFMA16
#undef TILE_BODY
}

// ------------------------------------------------------------ BN fold
__global__ void bnfold_kernel(const float* __restrict__ part, const float* __restrict__ g,
                              const float* __restrict__ bt, float* __restrict__ scsh) {
  int d = (blockIdx.x << 8) + threadIdx.x;    // grid 4
  float s = 0.f, s2 = 0.f;
  for (int j = 0; j < 128; ++j) { s += part[j * 2048 + d]; s2 += part[j * 2048 + 1024 + d]; }
  float mean = s * (1.f / 32768.f);
  float var  = s2 * (1.f / 32768.f) - mean * mean;
  float sc = g[d] * rsqrtf(var + 1e-5f);
  scsh[d] = sc;
  scsh[1024 + d] = bt[d] - mean * sc;
}

// y = prelu(y*sc + sh, p) [+ pos, prelu am], in place, 8 bf16/thread,
// grid-stride (2048 blocks x 8 iters).
template<bool MIX>
__global__ void bnact_kernel(ushort* __restrict__ Y, const float* __restrict__ scsh,
                             const float* __restrict__ p, const float* __restrict__ pos,
                             const float* __restrict__ am) {
  float pp = p[0];
  float aa = MIX ? am[0] : 0.f;
#pragma unroll 1
  for (int it = 0; it < 8; ++it) {
    size_t vi = ((size_t)it << 19) + ((size_t)blockIdx.x << 8) + threadIdx.x;  // vec idx
    size_t i = vi << 3;
    int d = (int)(i & 1023);
    float pv[8];
    if (MIX) {
      int prow = (int)((i >> 10) & 255);
      const float4* pb = (const float4*)(pos + ((size_t)prow << 10) + d);
      float4 pA = pb[0], pB = pb[1];
      pv[0]=pA.x; pv[1]=pA.y; pv[2]=pA.z; pv[3]=pA.w;
      pv[4]=pB.x; pv[5]=pB.y; pv[6]=pB.z; pv[7]=pB.w;
    }
    uint4 raw = *(const uint4*)(Y + i);
    uint32_t w[4] = {raw.x, raw.y, raw.z, raw.w};
    uint32_t o[4];
#pragma unroll
    for (int q = 0; q < 4; ++q) {
      int dd = d + q * 2;
      float v0 = bf2f(w[q] & 0xFFFFu) * scsh[dd]     + scsh[1024 + dd];
      float v1 = bf2f(w[q] >> 16)     * scsh[dd + 1] + scsh[1024 + dd + 1];
      v0 = v0 > 0.f ? v0 : pp * v0;
      v1 = v1 > 0.f ? v1 : pp * v1;
      if (MIX) {
        v0 += pv[2 * q];     v1 += pv[2 * q + 1];
        v0 = v0 > 0.f ? v0 : aa * v0;
        v1 = v1 > 0.f ? v1 : aa * v1;
      }
      o[q] = (uint32_t)f2bf(v0) | ((uint32_t)f2bf(v1) << 16);
    }
    *(uint4*)(Y + i) = make_uint4(o[0], o[1], o[2], o[3]);
  }
}

// ----------------------------------------------------------- fused preprocessing
// blocks [0,2048): im2col (16 tokens each, K padded 147->192)
// blocks [2048,4096): w1,w2,w3,wm -> bf16
// blocks [4096,4224): invperm
// blocks [4224,5248): padw0 (w0 -> bf16, K padded 147->192)
__global__ void prep_kernel(const float* __restrict__ x,
                            const float* __restrict__ w0, const float* __restrict__ w1,
                            const float* __restrict__ w2, const float* __restrict__ w3,
                            const float* __restrict__ wm, const int* __restrict__ perm,
                            ushort* __restrict__ P, ushort* __restrict__ w0b,
                            ushort* __restrict__ w1b, ushort* __restrict__ w2b,
                            ushort* __restrict__ w3b, ushort* __restrict__ wmb,
                            int* __restrict__ inv) {
  const int b = blockIdx.x, tid = threadIdx.x;
  if (b < 2048) {
    if (tid < 192) {
      int t0 = b << 4;
#pragma unroll 1
      for (int tt = 0; tt < 16; ++tt) {
        int t = t0 + tt;
        ushort v = 0;
        if (tid < 147) {
          int bb = t >> 8, pidx = t & 255;
          int pi = pidx >> 4, pj = pidx & 15;
          int cin = tid / 49, rem = tid - cin * 49;
          int dy = rem / 7, dx = rem - dy * 7;
          v = f2bf(x[(size_t)(bb * 3 + cin) * 12544 + (size_t)(pi * 7 + dy) * 112 + (pj * 7 + dx)]);
        }
        P[(size_t)t * 192 + tid] = v;
      }
    }
  } else if (b < 4096) {
    int i = ((b - 2048) << 8) + tid;           // [0, 524288)
#pragma unroll
    for (int r = 0; r < 2; ++r) {
      int idx = (r << 19) + i;
      w1b[idx] = f2bf(w1[idx]);
      w2b[idx] = f2bf(w2[idx]);
      w3b[idx] = f2bf(w3[idx]);
    }
    wmb[i] = f2bf(wm[i]);
  } else if (b < 4224) {
    int t = ((b - 4096) << 8) + tid;           // [0, 32768)
    inv[(t & ~255) + perm[t]] = t & 255;
  } else {
    int d = b - 4224;                          // [0, 1024)
    if (tid < 192)
      w0b[d * 192 + tid] = (tid < 147) ? f2bf(w0[d * 147 + tid]) : (ushort)0;
  }
}

extern "C" void kernel_launch(void* const* d_in, const int* in_sizes, int n_in,
                              void* d_out, int out_size, void* d_ws, size_t ws_size,
                              hipStream_t stream) {
  const float* x   = (const float*)d_in[0];
  const float* w0  = (const float*)d_in[1];
  const float* b0  = (const float*)d_in[2];
  const float* a0  = (const float*)d_in[3];
  const float* w1  = (const float*)d_in[4];
  const float* b1  = (const float*)d_in[5];
  const float* g1  = (const float*)d_in[6];
  const float* bt1 = (const float*)d_in[7];
  const float* p1  = (const float*)d_in[8];
  const float* w2  = (const float*)d_in[9];
  const float* b2  = (const float*)d_in[10];
  const float* g2  = (const float*)d_in[11];
  const float* bt2 = (const float*)d_in[12];
  const float* p2  = (const float*)d_in[13];
  const float* w3  = (const float*)d_in[14];
  const float* b3  = (const float*)d_in[15];
  const float* g3  = (const float*)d_in[16];
  const float* bt3 = (const float*)d_in[17];
  const float* p3  = (const float*)d_in[18];
  const float* pos = (const float*)d_in[19];
  const float* am  = (const float*)d_in[20];
  const float* wm  = (const float*)d_in[21];
  const float* bm  = (const float*)d_in[22];
  const int*  perm = (const int*)d_in[23];

  char* ws = (char*)d_ws;
  ushort* B0   = (ushort*)ws;                                   // 64MB
  ushort* B1   = (ushort*)(ws + 67108864);                      // 64MB
  float*  part = (float*)(ws + 134217728);                      // 1MB (2MB rsvd)
  float*  scsh = (float*)(ws + 134217728 + 2097152);            // 8KB
  int*    inv  = (int*)  (ws + 134217728 + 2097152 + 8192);     // 128KB
  char*   wb   = ws + 134217728 + 2097152 + 8192 + 131072;
  ushort* w1b  = (ushort*)wb;                                   // 2MB
  ushort* w2b  = w1b + 1048576;                                 // 2MB
  ushort* w3b  = w2b + 1048576;                                 // 2MB
  ushort* wmb  = w3b + 1048576;                                 // 1MB
  ushort* w0b  = wmb + 524288;                                  // 384KB (1024x192)

  // ---- all preprocessing in one dispatch ----
  prep_kernel<<<dim3(5248), dim3(256), 0, stream>>>(
      x, w0, w1, w2, w3, wm, perm, B1, w0b, w1b, w2b, w3b, wmb, inv);

  // patch-embed conv as GEMM: P(B1) x w0^T -> act0(B0), bias+prelu  (K=192)
  gemm_kernel<0, 2, 192, 1024><<<dim3(512), dim3(512), 0, stream>>>(
      B1, w0b, b0, a0, (void*)B0, nullptr, nullptr);

  // layer 1: B0 -> B1  (stats fused)
  gemm_kernel<1, 2, 1024, 1024><<<dim3(512), dim3(512), 0, stream>>>(
      B0, w1b, b1, nullptr, (void*)B1, part, nullptr);
  bnfold_kernel<<<dim3(4), dim3(256), 0, stream>>>(part, g1, bt1, scsh);
  bnact_kernel<false><<<dim3(2048), dim3(256), 0, stream>>>(B1, scsh, p1, nullptr, nullptr);

  // layer 2: B1 -> B0
  gemm_kernel<1, 2, 1024, 1024><<<dim3(512), dim3(512), 0, stream>>>(
      B1, w2b, b2, nullptr, (void*)B0, part, nullptr);
  bnfold_kernel<<<dim3(4), dim3(256), 0, stream>>>(part, g2, bt2, scsh);
  bnact_kernel<false><<<dim3(2048), dim3(256), 0, stream>>>(B0, scsh, p2, nullptr, nullptr);

  // layer 3: B0 -> B1, bnact fused with +pos & prelu(am)
  gemm_kernel<1, 2, 1024, 1024><<<dim3(512), dim3(512), 0, stream>>>(
      B0, w3b, b3, nullptr, (void*)B1, part, nullptr);
  bnfold_kernel<<<dim3(4), dim3(256), 0, stream>>>(part, g3, bt3, scsh);
  bnact_kernel<true><<<dim3(2048), dim3(256), 0, stream>>>(B1, scsh, p3, pos, am);

  // mixer: out = (enc @ wm^T + bm) rows scattered via inv -> d_out (fp32)
  gemm_kernel<2, 1, 1024, 512><<<dim3(256), dim3(512), 0, stream>>>(
      B1, wmb, bm, nullptr, d_out, nullptr, inv);
}